// Round 1
// baseline (3683.240 us; speedup 1.0000x reference)
//
#include <hip/hip_runtime.h>
#include <hip/hip_bf16.h>

// CirculantElmanCell: T=1024, B=16, D=2048
// out0: output [T,B,D] f32 ; out1: h [T+1,B,D] f32 (concatenated in d_out)

typedef __attribute__((ext_vector_type(8))) unsigned short us8;
typedef __attribute__((ext_vector_type(8))) __bf16 bf16x8;
typedef __attribute__((ext_vector_type(4))) float f32x4;

__device__ __forceinline__ int PADI(int a){ return a + (a >> 3); }   // LDS anti-bank-conflict pad

__device__ __forceinline__ unsigned short f2bf(float f){
  unsigned int u = __float_as_uint(f);
  return (unsigned short)((u + 0x7FFFu + ((u >> 16) & 1u)) >> 16);
}

__device__ __forceinline__ void sincos2pi(float fr, float& sn, float& co){
#if __has_builtin(__builtin_amdgcn_sinf) && __has_builtin(__builtin_amdgcn_cosf)
  sn = __builtin_amdgcn_sinf(fr);   // v_sin_f32: input in revolutions
  co = __builtin_amdgcn_cosf(fr);
#else
  __sincosf(fr * 6.28318530717958647692f, &sn, &co);
#endif
}

__device__ __forceinline__ float2 cmul(float2 a, float2 b){
  return make_float2(a.x*b.x - a.y*b.y, a.x*b.y + a.y*b.x);
}
__device__ __forceinline__ float2 cadd(float2 a, float2 b){ return make_float2(a.x+b.x, a.y+b.y); }
__device__ __forceinline__ float2 csub(float2 a, float2 b){ return make_float2(a.x-b.x, a.y-b.y); }

__device__ __forceinline__ float tanh_fast(float x){
  float e = __expf(2.0f * x);
  return 1.0f - 2.0f / (e + 1.0f);
}

// ---------- radix-4 Stockham stage, N=1024 complex, 256 threads, all buffers padded ----------
// stage (L, r=4, M): reads src[k+M*(j+L*q)], DFT4 with sign SGN, twiddle e^{SGN*2pi i * p*j*M/1024},
// writes dst[k+M*(4j+p)].  L*M == 256 (one butterfly per thread).
template<int L, int M, int SGN>
__device__ __forceinline__ void stage4(const float2* src, float2* dst, int tid){
  const int j  = tid / M;
  const int k  = tid - j * M;
  const int i0 = k + M * j;
  float2 c0 = src[PADI(i0)];
  float2 c1 = src[PADI(i0 +     M * L)];
  float2 c2 = src[PADI(i0 + 2 * M * L)];
  float2 c3 = src[PADI(i0 + 3 * M * L)];
  float2 sA = cadd(c0, c2), sB = csub(c0, c2);
  float2 sC = cadd(c1, c3), sD = csub(c1, c3);
  float2 iD = make_float2(-(float)SGN * sD.y, (float)SGN * sD.x);  // SGN*i*sD
  float2 X0 = cadd(sA, sC);
  float2 X2 = csub(sA, sC);
  float2 X1 = cadd(sB, iD);
  float2 X3 = csub(sB, iD);
  if (L > 1){
    float sn, co; sincos2pi((float)(j * M) * (1.0f / 1024.0f), sn, co);
    float2 w1 = make_float2(co, (float)SGN * sn);
    float2 w2 = cmul(w1, w1);
    float2 w3 = cmul(w2, w1);
    X1 = cmul(X1, w1); X2 = cmul(X2, w2); X3 = cmul(X3, w3);
  }
  const int o0 = k + M * 4 * j;
  dst[PADI(o0)]         = X0;
  dst[PADI(o0 +     M)] = X1;
  dst[PADI(o0 + 2 * M)] = X2;
  dst[PADI(o0 + 3 * M)] = X3;
}

// ---------- middle stage: Hermitian unpack of Z=FFT1024(z), multiply by lam (= fft_c/2048),
// repack to W so that unnormalized conj-FFT1024(W) = interleaved real result ----------
__device__ __forceinline__ void midstage(const float2* Z, float2* Wd, const float2* lam, int tid){
  #pragma unroll
  for (int u = 0; u < 4; ++u){
    int k  = tid + 256 * u;
    int kp = (1024 - k) & 1023;
    float2 zk = Z[PADI(k)], zp = Z[PADI(kp)];
    float2 E = make_float2(0.5f * (zk.x + zp.x),  0.5f * (zk.y - zp.y));
    float2 O = make_float2(0.5f * (zk.y + zp.y), -0.5f * (zk.x - zp.x));
    float sn, co; sincos2pi((float)k * (1.0f / 2048.0f), sn, co);
    float2 w  = make_float2(co, -sn);            // e^{-2pi i k/2048}
    float2 wO = cmul(w, O);
    float2 Hk  = cadd(E, wO);                    // H[k]
    float2 Hk2 = csub(E, wO);                    // H[k+1024]
    float2 Yk  = cmul(Hk,  lam[PADI(k)]);
    float2 Yk2 = cmul(Hk2, lam[PADI(k + 1024)]);
    float2 S  = cadd(Yk, Yk2);
    float2 Dd = csub(Yk, Yk2);
    float2 cw = make_float2(w.x, -w.y);          // conj(w)
    float2 cd = cmul(cw, Dd);
    Wd[PADI(k)] = make_float2(S.x - cd.y, S.y + cd.x);  // S + i*cd
  }
}

// final inverse radix-4 stage (L=1,M=256), results in registers: ys[p] = y[tid+256p]
__device__ __forceinline__ void final4(const float2* bB, int tid, float2 ys[4]){
  float2 c0 = bB[PADI(tid)];
  float2 c1 = bB[PADI(tid + 256)];
  float2 c2 = bB[PADI(tid + 512)];
  float2 c3 = bB[PADI(tid + 768)];
  float2 sA = cadd(c0, c2), sB = csub(c0, c2);
  float2 sC = cadd(c1, c3), sD = csub(c1, c3);
  float2 iD = make_float2(-sD.y, sD.x);          // SGN=+1
  ys[0] = cadd(sA, sC);
  ys[1] = cadd(sB, iD);
  ys[2] = csub(sA, sC);
  ys[3] = csub(sB, iD);
}

#define FFT_CONV_BODY(ZBUF) \
    stage4<256,  1, -1>(ZBUF, bA, tid); __syncthreads(); \
    stage4< 64,  4, -1>(bA,   bB, tid); __syncthreads(); \
    stage4< 16, 16, -1>(bB,   bA, tid); __syncthreads(); \
    stage4<  4, 64, -1>(bA,   bB, tid); __syncthreads(); \
    stage4<  1,256, -1>(bB,   bA, tid); __syncthreads(); \
    midstage(bA, bB, lam, tid);         __syncthreads(); \
    stage4<256,  1,  1>(bB,   bA, tid); __syncthreads(); \
    stage4< 64,  4,  1>(bA,   bB, tid); __syncthreads(); \
    stage4< 16, 16,  1>(bB,   bA, tid); __syncthreads(); \
    stage4<  4, 64,  1>(bA,   bB, tid); __syncthreads();

// ---------------- f32 -> bf16 bulk convert (8 elems/thread) ----------------
__global__ __launch_bounds__(256) void cvt_bf16(const float* __restrict__ in,
                                                unsigned short* __restrict__ out, int n8){
  int i = blockIdx.x * 256 + threadIdx.x;
  if (i >= n8) return;
  float4 a = ((const float4*)in)[2 * i];
  float4 b = ((const float4*)in)[2 * i + 1];
  us8 r;
  r[0] = f2bf(a.x); r[1] = f2bf(a.y); r[2] = f2bf(a.z); r[3] = f2bf(a.w);
  r[4] = f2bf(b.x); r[5] = f2bf(b.y); r[6] = f2bf(b.z); r[7] = f2bf(b.w);
  ((us8*)out)[i] = r;
}

// ---------------- lam[k] = fft(c)[k] / 2048, k in [0,2048) ----------------
__global__ __launch_bounds__(256) void dft_c(const float* __restrict__ c, float2* __restrict__ lam){
  __shared__ float cs[2048];
  int tid = threadIdx.x;
  for (int i = tid; i < 2048; i += 256) cs[i] = c[i];
  __syncthreads();
  int k = blockIdx.x * 256 + tid;
  float sr = 0.f, si = 0.f;
  for (int j = 0; j < 2048; ++j){
    int ph = (j * k) & 2047;              // exact phase reduction
    float sn, co; sincos2pi((float)ph * (1.0f / 2048.0f), sn, co);
    float cv = cs[j];
    sr = __fmaf_rn(cv,  co, sr);
    si = __fmaf_rn(-cv, sn, si);
  }
  lam[k] = make_float2(sr * (1.0f / 2048.0f), si * (1.0f / 2048.0f));
}

// ---------------- circ_x: pre[row] = ifft(lamx*fft(x_row)) + b  (8 rows / block) ----------------
__global__ __launch_bounds__(256) void circx(const float* __restrict__ x,
                                             const float* __restrict__ bias,
                                             const float2* __restrict__ lam_g,
                                             float* __restrict__ pre){
  __shared__ float2 rz[1151], bA[1151], bB[1151];
  __shared__ float2 lam[2303];
  const int tid = threadIdx.x;
  for (int i = tid; i < 2048; i += 256) lam[PADI(i)] = lam_g[i];
  for (int r = 0; r < 8; ++r){
    const size_t row = (size_t)blockIdx.x * 8 + r;
    const float2* xr = (const float2*)(x + row * 2048);
    for (int i = tid; i < 1024; i += 256) rz[PADI(i)] = xr[i];
    __syncthreads();
    FFT_CONV_BODY(rz)
    float2 ys[4]; final4(bB, tid, ys);
    float2* prow = (float2*)(pre + row * 2048);
    #pragma unroll
    for (int p = 0; p < 4; ++p){
      int n = tid + 256 * p;
      float2 bv = *(const float2*)(bias + 2 * n);
      prow[n] = make_float2(ys[p].x + bv.x, ys[p].y + bv.y);
    }
    __syncthreads();
  }
}

// ---------------- gate GEMM: g = silu(xb @ Wb^T + bg), written to h rows 1..T (f32) ----------------
__global__ __launch_bounds__(256) void gemm_gate(const unsigned short* __restrict__ A,  // [16384][2048] bf16
                                                 const unsigned short* __restrict__ B,  // [2048][2048] bf16 (row n, col k)
                                                 const float* __restrict__ bg,
                                                 float* __restrict__ houtp){
  __shared__ unsigned short As[128 * 32];
  __shared__ unsigned short Bs[128 * 32];
  const int tid  = threadIdx.x;
  const int lane = tid & 63;
  const int wave = tid >> 6;
  const int wr = wave >> 1, wc = wave & 1;
  const int m0 = blockIdx.x * 128, n0 = blockIdx.y * 128;

  const int srow = tid >> 1;
  const int scol = (tid & 1) << 4;
  const unsigned short* ga = A + (size_t)(m0 + srow) * 2048 + scol;
  const unsigned short* gb = B + (size_t)(n0 + srow) * 2048 + scol;
  unsigned short* la = As + srow * 32 + scol;
  unsigned short* lb = Bs + srow * 32 + scol;

  f32x4 acc[4][4];
  #pragma unroll
  for (int m = 0; m < 4; ++m)
    #pragma unroll
    for (int n = 0; n < 4; ++n)
      acc[m][n] = f32x4{0.f, 0.f, 0.f, 0.f};

  const int arow = wr * 64 + (lane & 15);
  const int brow = wc * 64 + (lane & 15);
  const int koff = (lane >> 4) * 8;

  for (int ks = 0; ks < 64; ++ks){
    const int k0 = ks * 32;
    us8 va0 = *(const us8*)(ga + k0);
    us8 va1 = *(const us8*)(ga + k0 + 8);
    us8 vb0 = *(const us8*)(gb + k0);
    us8 vb1 = *(const us8*)(gb + k0 + 8);
    __syncthreads();
    *(us8*)(la)     = va0; *(us8*)(la + 8) = va1;
    *(us8*)(lb)     = vb0; *(us8*)(lb + 8) = vb1;
    __syncthreads();
    bf16x8 av[4], bv[4];
    #pragma unroll
    for (int m = 0; m < 4; ++m) av[m] = *(const bf16x8*)(As + (arow + m * 16) * 32 + koff);
    #pragma unroll
    for (int n = 0; n < 4; ++n) bv[n] = *(const bf16x8*)(Bs + (brow + n * 16) * 32 + koff);
    #pragma unroll
    for (int m = 0; m < 4; ++m)
      #pragma unroll
      for (int n = 0; n < 4; ++n)
        acc[m][n] = __builtin_amdgcn_mfma_f32_16x16x32_bf16(av[m], bv[n], acc[m][n], 0, 0, 0);
  }
  #pragma unroll
  for (int n = 0; n < 4; ++n){
    const int ng = n0 + wc * 64 + n * 16 + (lane & 15);
    const float bgv = bg[ng];
    #pragma unroll
    for (int m = 0; m < 4; ++m){
      const int mbase = m0 + wr * 64 + m * 16 + (lane >> 4) * 4;
      #pragma unroll
      for (int r = 0; r < 4; ++r){
        float v = acc[m][n][r] + bgv;
        float s = v / (1.0f + __expf(-v));
        houtp[(size_t)(mbase + r + 16) * 2048 + ng] = s;   // g row m -> h row m+16
      }
    }
  }
}

// ---------------- sequential recurrence: 1 block per batch row ----------------
__global__ __launch_bounds__(256) void recur(const float* __restrict__ h0,
                                             const float2* __restrict__ lam_g,
                                             float* __restrict__ outp,    // holds pre on entry, out on exit
                                             float* __restrict__ houtp){  // rows 1..T hold g, overwritten with h
  __shared__ float2 hz[1151], bA[1151], bB[1151];
  __shared__ float2 lam[2303];
  const int tid = threadIdx.x;
  const int b   = blockIdx.x;
  for (int i = tid; i < 2048; i += 256) lam[PADI(i)] = lam_g[i];
  {
    const float2* h02 = (const float2*)(h0 + (size_t)b * 2048);
    float2* hrow0 = (float2*)(houtp + (size_t)b * 2048);
    for (int i = tid; i < 1024; i += 256){ float2 v = h02[i]; hz[PADI(i)] = v; hrow0[i] = v; }
  }
  __syncthreads();
  #pragma unroll 1
  for (int t = 0; t < 1024; ++t){
    float2* orow = (float2*)(outp  + ((size_t)t * 16 + b) * 2048);
    float2* hrow = (float2*)(houtp + ((size_t)(t + 1) * 16 + b) * 2048);
    float2 pr[4], gv[4];
    #pragma unroll
    for (int p = 0; p < 4; ++p){ int n = tid + 256 * p; pr[p] = orow[n]; gv[p] = hrow[n]; }
    FFT_CONV_BODY(hz)
    float2 ys[4]; final4(bB, tid, ys);
    #pragma unroll
    for (int p = 0; p < 4; ++p){
      int n = tid + 256 * p;
      float hn0 = tanh_fast(ys[p].x + pr[p].x);
      float hn1 = tanh_fast(ys[p].y + pr[p].y);
      float2 hv = make_float2(hn0, hn1);
      hz[PADI(n)] = hv;
      hrow[n] = hv;
      orow[n] = make_float2(hn0 * gv[p].x, hn1 * gv[p].y);
    }
    __syncthreads();
  }
}

extern "C" void kernel_launch(void* const* d_in, const int* in_sizes, int n_in,
                              void* d_out, int out_size, void* d_ws, size_t ws_size,
                              hipStream_t stream){
  const float* x  = (const float*)d_in[0];
  const float* h0 = (const float*)d_in[1];
  const float* ch = (const float*)d_in[2];
  const float* cx = (const float*)d_in[3];
  const float* Wg = (const float*)d_in[4];
  const float* bb = (const float*)d_in[5];
  const float* bg = (const float*)d_in[6];
  float* outp  = (float*)d_out;                        // [T,B,D]
  float* houtp = outp + (size_t)1024 * 16 * 2048;      // [T+1,B,D]

  char* w = (char*)d_ws;
  unsigned short* xb = (unsigned short*)w; w += (size_t)16384 * 2048 * 2;
  unsigned short* Wb = (unsigned short*)w; w += (size_t)2048 * 2048 * 2;
  float2* lamh = (float2*)w; w += 2048 * sizeof(float2);
  float2* lamx = (float2*)w; w += 2048 * sizeof(float2);

  cvt_bf16 <<<dim3(16384), dim3(256), 0, stream>>>(x,  xb, 16384 * 2048 / 8);
  cvt_bf16 <<<dim3(2048),  dim3(256), 0, stream>>>(Wg, Wb,  2048 * 2048 / 8);
  dft_c    <<<dim3(8),     dim3(256), 0, stream>>>(ch, lamh);
  dft_c    <<<dim3(8),     dim3(256), 0, stream>>>(cx, lamx);
  circx    <<<dim3(2048),  dim3(256), 0, stream>>>(x, bb, lamx, outp);       // pre -> outp
  gemm_gate<<<dim3(128,16),dim3(256), 0, stream>>>(xb, Wb, bg, houtp);       // g -> h rows 1..T
  recur    <<<dim3(16),    dim3(256), 0, stream>>>(h0, lamh, outp, houtp);
}

// Round 2
// 3404.638 us; speedup vs baseline: 1.0818x; 1.0818x over previous
//
#include <hip/hip_runtime.h>
#include <hip/hip_bf16.h>

// CirculantElmanCell: T=1024, B=16, D=2048
// out0: output [T,B,D] f32 ; out1: h [T+1,B,D] f32 (concatenated in d_out)

typedef __attribute__((ext_vector_type(8))) unsigned short us8;
typedef __attribute__((ext_vector_type(8))) __bf16 bf16x8;
typedef __attribute__((ext_vector_type(4))) float f32x4;

__device__ __forceinline__ int SIG(int i){ return i + (i >> 4); }  // LDS swizzle: uniform-4/bank-pair

__device__ __forceinline__ unsigned short f2bf(float f){
  unsigned int u = __float_as_uint(f);
  return (unsigned short)((u + 0x7FFFu + ((u >> 16) & 1u)) >> 16);
}

__device__ __forceinline__ void sincos2pi(float fr, float& sn, float& co){
#if __has_builtin(__builtin_amdgcn_sinf) && __has_builtin(__builtin_amdgcn_cosf)
  sn = __builtin_amdgcn_sinf(fr);   // v_sin_f32: input in revolutions
  co = __builtin_amdgcn_cosf(fr);
#else
  __sincosf(fr * 6.28318530717958647692f, &sn, &co);
#endif
}

__device__ __forceinline__ float2 cmul(float2 a, float2 b){
  return make_float2(a.x*b.x - a.y*b.y, a.x*b.y + a.y*b.x);
}
__device__ __forceinline__ float2 cadd(float2 a, float2 b){ return make_float2(a.x+b.x, a.y+b.y); }
__device__ __forceinline__ float2 csub(float2 a, float2 b){ return make_float2(a.x-b.x, a.y-b.y); }

__device__ __forceinline__ float tanh_fast(float x){
  float e = __expf(2.0f * x);
  return 1.0f - 2.0f / (e + 1.0f);
}

// W_D^{sgn*num} = e^{sgn*2pi i num/D}
__device__ __forceinline__ float2 wn(int num, float dinv, int sgn){
  float sn, co; sincos2pi((float)num * dinv, sn, co);
  return make_float2(co, sgn > 0 ? sn : -sn);
}

template<int SGN>
__device__ __forceinline__ void dft4_full(const float2 a[4], float2 X[4]){
  float2 sA = cadd(a[0],a[2]), sB = csub(a[0],a[2]);
  float2 sC = cadd(a[1],a[3]), sD = csub(a[1],a[3]);
  float2 iD = make_float2(-(float)SGN*sD.y, (float)SGN*sD.x);
  X[0]=cadd(sA,sC); X[1]=cadd(sB,iD); X[2]=csub(sA,sC); X[3]=csub(sB,iD);
}

// Per-thread time-invariant constants (all in registers)
struct FSetup {
  float2 w16f[3], w16i[3];      // W16^{±(q1+1)*sub}
  float2 twA[4], twB[4], twD[4], twE[4];
  float2 wmd[4];                // W_2048^{-(tid+256q)}
  float2 lamA[4], lamB[4];      // lam[tid+256q], lam[tid+256q+1024]
};

__device__ __forceinline__ void make_setup(FSetup& S, int tid, const float2* __restrict__ lam_g){
  const int sub = tid & 3, bf = tid >> 2;
  #pragma unroll
  for (int i = 0; i < 3; ++i){
    S.w16f[i] = wn(((i + 1) * sub) & 15, 1.0f/16.0f, -1);
    S.w16i[i] = make_float2(S.w16f[i].x, -S.w16f[i].y);
  }
  #pragma unroll
  for (int p2 = 0; p2 < 4; ++p2){
    S.twA[p2] = wn((bf * (sub + 4*p2)) & 1023, 1.0f/1024.0f, -1);          // A: M=1, j=bf
    S.twB[p2] = wn((16 * (bf >> 4) * (sub + 4*p2)) & 1023, 1.0f/1024.0f, -1); // B: M=16, j=bf/16
    S.twD[p2] = wn((tid * p2) & 1023, 1.0f/1024.0f, +1);                   // inv1: j=tid, M=1
    S.twE[p2] = wn((4 * (bf >> 2) * (sub + 4*p2)) & 1023, 1.0f/1024.0f, +1); // E: M=4, j=bf/4
  }
  #pragma unroll
  for (int q = 0; q < 4; ++q){
    int k = tid + 256 * q;
    S.wmd[q]  = wn(k & 2047, 1.0f/2048.0f, -1);
    S.lamA[q] = lam_g[k];
    S.lamB[q] = lam_g[k + 1024];
  }
}

// Radix-16 Stockham stage: butterflies (j,k), bf=j*M+k, reads src[k+M*(j+L*q)],
// X_p = sum_q in_q W16^{SGN qp}, twiddle W_1024^{SGN j M p}, writes dst[k+M*(16j+p)].
// 4 threads/butterfly; thread computes p = sub + 4*p2.
template<int L, int M, int SGN>
__device__ __forceinline__ void r16(const float2* src, float2* dst, int bf, int sub,
                                    const float2* w16, const float2* tw){
  const int j = bf / M, k = bf - j * M;
  const int base = k + M * j;              // reads at base + 64*q  (M*L==64 always)
  float2 in[16];
  #pragma unroll
  for (int q = 0; q < 16; ++q) in[q] = src[SIG(base + 64 * q)];
  float2 Y[4];
  #pragma unroll
  for (int q1 = 0; q1 < 4; ++q1){
    float2 a0=in[q1], a1=in[q1+4], a2=in[q1+8], a3=in[q1+12];
    float2 sA=cadd(a0,a2), sB=csub(a0,a2), sC=cadd(a1,a3), sD=csub(a1,a3);
    float2 iD=make_float2(-(float)SGN*sD.y, (float)SGN*sD.x);
    float2 u = (sub & 1) ? sB : sA;
    float2 v = (sub & 1) ? iD : sC;
    Y[q1] = (sub & 2) ? csub(u, v) : cadd(u, v);
  }
  Y[1]=cmul(Y[1],w16[0]); Y[2]=cmul(Y[2],w16[1]); Y[3]=cmul(Y[3],w16[2]);
  float2 sA=cadd(Y[0],Y[2]), sB=csub(Y[0],Y[2]), sC=cadd(Y[1],Y[3]), sD=csub(Y[1],Y[3]);
  float2 iD=make_float2(-(float)SGN*sD.y, (float)SGN*sD.x);
  float2 X[4] = { cadd(sA,sC), cadd(sB,iD), csub(sA,sC), csub(sB,iD) };
  const int obase = k + M * (16 * j + sub);
  #pragma unroll
  for (int p2 = 0; p2 < 4; ++p2)
    dst[SIG(obase + 4 * M * p2)] = cmul(X[p2], tw[p2]);
}

// Final inverse stage (L=1,M=64,SGN=+1, no twiddle): outputs to registers.
// X[p2] sits at element index bf + 64*sub + 256*p2.
__device__ __forceinline__ void r16_final(const float2* src, int bf, int sub,
                                          const float2* w16, float2 X[4]){
  float2 in[16];
  #pragma unroll
  for (int q = 0; q < 16; ++q) in[q] = src[SIG(bf + 64 * q)];
  float2 Y[4];
  #pragma unroll
  for (int q1 = 0; q1 < 4; ++q1){
    float2 a0=in[q1], a1=in[q1+4], a2=in[q1+8], a3=in[q1+12];
    float2 sA=cadd(a0,a2), sB=csub(a0,a2), sC=cadd(a1,a3), sD=csub(a1,a3);
    float2 iD=make_float2(-sD.y, sD.x);
    float2 u = (sub & 1) ? sB : sA;
    float2 v = (sub & 1) ? iD : sC;
    Y[q1] = (sub & 2) ? csub(u, v) : cadd(u, v);
  }
  Y[1]=cmul(Y[1],w16[0]); Y[2]=cmul(Y[2],w16[1]); Y[3]=cmul(Y[3],w16[2]);
  float2 sA=cadd(Y[0],Y[2]), sB=csub(Y[0],Y[2]), sC=cadd(Y[1],Y[3]), sD=csub(Y[1],Y[3]);
  float2 iD=make_float2(-sD.y, sD.x);
  X[0]=cadd(sA,sC); X[1]=cadd(sB,iD); X[2]=csub(sA,sC); X[3]=csub(sB,iD);
}

// Fused phase D: fwd stage C (r4,L=1,M=256) for butterflies {t, 256-t} in-reg,
// Hermitian-unpack * lam * repack (mid), inv stage 1 (r4,L=256,M=1) for j=t.
__device__ __forceinline__ void phaseD(const float2* src, float2* dst, int tid, const FSetup& S){
  const int k2 = (256 - tid) & 255;
  float2 a0[4], b0[4];
  #pragma unroll
  for (int q = 0; q < 4; ++q){
    a0[q] = src[SIG(tid + 256*q)];
    b0[q] = src[SIG(k2  + 256*q)];
  }
  float2 Z1[4], Z2[4];
  dft4_full<-1>(a0, Z1);
  dft4_full<-1>(b0, Z2);
  float2 Wv[4];
  #pragma unroll
  for (int q = 0; q < 4; ++q){
    float2 zk = Z1[q];
    float2 zp = Z2[3 - q];
    if (tid == 0) zp = Z2[(4 - q) & 3];   // self-mirror special case
    float2 E = make_float2(0.5f*(zk.x+zp.x),  0.5f*(zk.y-zp.y));
    float2 O = make_float2(0.5f*(zk.y+zp.y), -0.5f*(zk.x-zp.x));
    float2 w = S.wmd[q];
    float2 wO = cmul(w, O);
    float2 Hk  = cadd(E, wO), Hk2 = csub(E, wO);
    float2 Yk  = cmul(Hk,  S.lamA[q]);
    float2 Yk2 = cmul(Hk2, S.lamB[q]);
    float2 Sm = cadd(Yk, Yk2), Dd = csub(Yk, Yk2);
    float2 cw = make_float2(w.x, -w.y);
    float2 cd = cmul(cw, Dd);
    Wv[q] = make_float2(Sm.x - cd.y, Sm.y + cd.x);
  }
  float2 X[4]; dft4_full<1>(Wv, X);
  #pragma unroll
  for (int p = 0; p < 4; ++p) dst[SIG(4*tid + p)] = cmul(X[p], S.twD[p]);
}

// Phases A,B,D,E (leaves final-stage input in bB). 4 internal barriers.
__device__ __forceinline__ void fft5_phases(float2* hz, float2* bA, float2* bB,
                                            int tid, const FSetup& S){
  const int bf = tid >> 2, sub = tid & 3;
  r16<64,  1, -1>(hz, bA, bf, sub, S.w16f, S.twA); __syncthreads();
  r16< 4, 16, -1>(bA, bB, bf, sub, S.w16f, S.twB); __syncthreads();
  phaseD(bB, bA, tid, S);                          __syncthreads();
  r16<16,  4,  1>(bA, bB, bf, sub, S.w16i, S.twE); __syncthreads();
}

// ---------------- f32 -> bf16 bulk convert (8 elems/thread) ----------------
__global__ __launch_bounds__(256) void cvt_bf16(const float* __restrict__ in,
                                                unsigned short* __restrict__ out, int n8){
  int i = blockIdx.x * 256 + threadIdx.x;
  if (i >= n8) return;
  float4 a = ((const float4*)in)[2 * i];
  float4 b = ((const float4*)in)[2 * i + 1];
  us8 r;
  r[0] = f2bf(a.x); r[1] = f2bf(a.y); r[2] = f2bf(a.z); r[3] = f2bf(a.w);
  r[4] = f2bf(b.x); r[5] = f2bf(b.y); r[6] = f2bf(b.z); r[7] = f2bf(b.w);
  ((us8*)out)[i] = r;
}

// ---------------- lam[k] = fft(c)[k] / 2048, k in [0,2048) ----------------
__global__ __launch_bounds__(256) void dft_c(const float* __restrict__ c, float2* __restrict__ lam){
  __shared__ float cs[2048];
  int tid = threadIdx.x;
  for (int i = tid; i < 2048; i += 256) cs[i] = c[i];
  __syncthreads();
  int k = blockIdx.x * 256 + tid;
  float sr = 0.f, si = 0.f;
  for (int j = 0; j < 2048; ++j){
    int ph = (j * k) & 2047;
    float sn, co; sincos2pi((float)ph * (1.0f / 2048.0f), sn, co);
    float cv = cs[j];
    sr = __fmaf_rn(cv,  co, sr);
    si = __fmaf_rn(-cv, sn, si);
  }
  lam[k] = make_float2(sr * (1.0f / 2048.0f), si * (1.0f / 2048.0f));
}

// ---------------- circ_x: pre[row] = ifft(lamx*fft(x_row)) + b  (8 rows/block) ----------------
__global__ __launch_bounds__(256, 2) void circx(const float* __restrict__ x,
                                                const float* __restrict__ bias,
                                                const float2* __restrict__ lam_g,
                                                float* __restrict__ pre){
  __shared__ float2 hz[1088], bA[1088], bB[1088];
  const int tid = threadIdx.x;
  FSetup S; make_setup(S, tid, lam_g);
  const int bf = tid >> 2, sub = tid & 3;
  const int i0 = bf + 64 * sub;
  float2 bv[4];
  #pragma unroll
  for (int p2 = 0; p2 < 4; ++p2) bv[p2] = ((const float2*)bias)[i0 + 256*p2];
  for (int r = 0; r < 8; ++r){
    const size_t row = (size_t)blockIdx.x * 8 + r;
    const float2* xr = (const float2*)(x + row * 2048);
    for (int i = tid; i < 1024; i += 256) hz[SIG(i)] = xr[i];
    __syncthreads();
    fft5_phases(hz, bA, bB, tid, S);
    float2 X[4]; r16_final(bB, bf, sub, S.w16i, X);
    float2* prow = (float2*)(pre + row * 2048);
    #pragma unroll
    for (int p2 = 0; p2 < 4; ++p2){
      int n = i0 + 256*p2;
      prow[n] = make_float2(X[p2].x + bv[p2].x, X[p2].y + bv[p2].y);
    }
    __syncthreads();
  }
}

// ---------------- gate GEMM: g = silu(xb @ Wb^T + bg) -> h rows 1..T ----------------
__global__ __launch_bounds__(256) void gemm_gate(const unsigned short* __restrict__ A,
                                                 const unsigned short* __restrict__ B,
                                                 const float* __restrict__ bg,
                                                 float* __restrict__ houtp){
  __shared__ unsigned short As[128 * 32];
  __shared__ unsigned short Bs[128 * 32];
  const int tid  = threadIdx.x;
  const int lane = tid & 63;
  const int wave = tid >> 6;
  const int wr = wave >> 1, wc = wave & 1;
  const int m0 = blockIdx.x * 128, n0 = blockIdx.y * 128;

  const int srow = tid >> 1;
  const int scol = (tid & 1) << 4;
  const unsigned short* ga = A + (size_t)(m0 + srow) * 2048 + scol;
  const unsigned short* gb = B + (size_t)(n0 + srow) * 2048 + scol;
  unsigned short* la = As + srow * 32 + scol;
  unsigned short* lb = Bs + srow * 32 + scol;

  f32x4 acc[4][4];
  #pragma unroll
  for (int m = 0; m < 4; ++m)
    #pragma unroll
    for (int n = 0; n < 4; ++n)
      acc[m][n] = f32x4{0.f, 0.f, 0.f, 0.f};

  const int arow = wr * 64 + (lane & 15);
  const int brow = wc * 64 + (lane & 15);
  const int koff = (lane >> 4) * 8;

  for (int ks = 0; ks < 64; ++ks){
    const int k0 = ks * 32;
    us8 va0 = *(const us8*)(ga + k0);
    us8 va1 = *(const us8*)(ga + k0 + 8);
    us8 vb0 = *(const us8*)(gb + k0);
    us8 vb1 = *(const us8*)(gb + k0 + 8);
    __syncthreads();
    *(us8*)(la)     = va0; *(us8*)(la + 8) = va1;
    *(us8*)(lb)     = vb0; *(us8*)(lb + 8) = vb1;
    __syncthreads();
    bf16x8 av[4], bv[4];
    #pragma unroll
    for (int m = 0; m < 4; ++m) av[m] = *(const bf16x8*)(As + (arow + m * 16) * 32 + koff);
    #pragma unroll
    for (int n = 0; n < 4; ++n) bv[n] = *(const bf16x8*)(Bs + (brow + n * 16) * 32 + koff);
    #pragma unroll
    for (int m = 0; m < 4; ++m)
      #pragma unroll
      for (int n = 0; n < 4; ++n)
        acc[m][n] = __builtin_amdgcn_mfma_f32_16x16x32_bf16(av[m], bv[n], acc[m][n], 0, 0, 0);
  }
  #pragma unroll
  for (int n = 0; n < 4; ++n){
    const int ng = n0 + wc * 64 + n * 16 + (lane & 15);
    const float bgv = bg[ng];
    #pragma unroll
    for (int m = 0; m < 4; ++m){
      const int mbase = m0 + wr * 64 + m * 16 + (lane >> 4) * 4;
      #pragma unroll
      for (int r = 0; r < 4; ++r){
        float v = acc[m][n][r] + bgv;
        float s = v / (1.0f + __expf(-v));
        houtp[(size_t)(mbase + r + 16) * 2048 + ng] = s;
      }
    }
  }
}

// ---------------- sequential recurrence: 1 block per batch row ----------------
__global__ __launch_bounds__(256, 1) void recur(const float* __restrict__ h0,
                                                const float2* __restrict__ lam_g,
                                                float* __restrict__ outp,    // pre on entry, out on exit
                                                float* __restrict__ houtp){  // rows 1..T: g -> h
  __shared__ float2 hz[1088], bA[1088], bB[1088];
  const int tid = threadIdx.x;
  const int b   = blockIdx.x;
  FSetup S; make_setup(S, tid, lam_g);
  {
    const float2* h02 = (const float2*)(h0 + (size_t)b * 2048);
    float2* hrow0 = (float2*)(houtp + (size_t)b * 2048);
    for (int i = tid; i < 1024; i += 256){ float2 v = h02[i]; hz[SIG(i)] = v; hrow0[i] = v; }
  }
  __syncthreads();
  const int bf = tid >> 2, sub = tid & 3;
  const int i0 = bf + 64 * sub;
  #pragma unroll 1
  for (int t = 0; t < 1024; ++t){
    float2* orow = (float2*)(outp  + ((size_t)t * 16 + b) * 2048);
    float2* hrow = (float2*)(houtp + ((size_t)(t + 1) * 16 + b) * 2048);
    float2 pr[4], gv[4];
    #pragma unroll
    for (int p2 = 0; p2 < 4; ++p2){ pr[p2] = orow[i0 + 256*p2]; gv[p2] = hrow[i0 + 256*p2]; }
    fft5_phases(hz, bA, bB, tid, S);
    float2 X[4]; r16_final(bB, bf, sub, S.w16i, X);
    #pragma unroll
    for (int p2 = 0; p2 < 4; ++p2){
      int n = i0 + 256*p2;
      float h0v = tanh_fast(X[p2].x + pr[p2].x);
      float h1v = tanh_fast(X[p2].y + pr[p2].y);
      float2 hv = make_float2(h0v, h1v);
      hz[SIG(n)] = hv;
      hrow[n] = hv;
      orow[n] = make_float2(h0v * gv[p2].x, h1v * gv[p2].y);
    }
    __syncthreads();
  }
}

extern "C" void kernel_launch(void* const* d_in, const int* in_sizes, int n_in,
                              void* d_out, int out_size, void* d_ws, size_t ws_size,
                              hipStream_t stream){
  const float* x  = (const float*)d_in[0];
  const float* h0 = (const float*)d_in[1];
  const float* ch = (const float*)d_in[2];
  const float* cx = (const float*)d_in[3];
  const float* Wg = (const float*)d_in[4];
  const float* bb = (const float*)d_in[5];
  const float* bg = (const float*)d_in[6];
  float* outp  = (float*)d_out;                        // [T,B,D]
  float* houtp = outp + (size_t)1024 * 16 * 2048;      // [T+1,B,D]

  char* w = (char*)d_ws;
  unsigned short* xb = (unsigned short*)w; w += (size_t)16384 * 2048 * 2;
  unsigned short* Wb = (unsigned short*)w; w += (size_t)2048 * 2048 * 2;
  float2* lamh = (float2*)w; w += 2048 * sizeof(float2);
  float2* lamx = (float2*)w; w += 2048 * sizeof(float2);

  cvt_bf16 <<<dim3(16384), dim3(256), 0, stream>>>(x,  xb, 16384 * 2048 / 8);
  cvt_bf16 <<<dim3(2048),  dim3(256), 0, stream>>>(Wg, Wb,  2048 * 2048 / 8);
  dft_c    <<<dim3(8),     dim3(256), 0, stream>>>(ch, lamh);
  dft_c    <<<dim3(8),     dim3(256), 0, stream>>>(cx, lamx);
  circx    <<<dim3(2048),  dim3(256), 0, stream>>>(x, bb, lamx, outp);       // pre -> outp
  gemm_gate<<<dim3(128,16),dim3(256), 0, stream>>>(xb, Wb, bg, houtp);       // g -> h rows 1..T
  recur    <<<dim3(16),    dim3(256), 0, stream>>>(h0, lamh, outp, houtp);
}